// Round 3
// baseline (426.294 us; speedup 1.0000x reference)
//
#include <hip/hip_runtime.h>

// MapDensePoseTex, two-pass plane-blocked version, 16 pixels/thread for MLP.
// tex (8,16,512,512) f32, iuv (8,3,512,512) i32, lut (24,256,256,2) f32,
// tex_res = 512. Output (8,16,512,512) f32.
//
// Pass 1: per-pixel offset = vI*R+uI (or -1 if masked) -> d_ws (B*H*W int32).
//         16 pixels/thread -> 16 independent lut gathers in flight.
// Pass 2: one block gathers 4096 pixels of ONE (b,c) plane (16 px/thread ->
//         16 independent tex gathers in flight); block-id swizzle pins each
//         plane's blocks to one XCD (blockIdx%8 -> XCD round-robin) so the
//         1 MB plane stays L2-resident.

#define N_PARTS 24

__global__ __launch_bounds__(256) void dp_offsets_kernel(
    const int*   __restrict__ iuv,
    const float* __restrict__ lut,
    int*         __restrict__ offs,
    int R)
{
    constexpr int H = 512, W = 512;
    const float scale = (float)(R - 1);
    const size_t hw = (size_t)H * W;

    const int t = blockIdx.x * blockDim.x + threadIdx.x;   // one thread = 16 px
    const int pix = t * 16;
    const int b = pix >> 18;                // /(H*W), H*W = 262144
    const int p = pix & (int)(hw - 1);

    const size_t ibase = (size_t)b * 3 * hw + p;

    int4 p4[4], u4[4], v4[4];
    #pragma unroll
    for (int g = 0; g < 4; ++g) p4[g] = *(const int4*)(iuv + ibase + g * 4);
    #pragma unroll
    for (int g = 0; g < 4; ++g) u4[g] = *(const int4*)(iuv + ibase + hw + g * 4);
    #pragma unroll
    for (int g = 0; g < 4; ++g) v4[g] = *(const int4*)(iuv + ibase + 2 * hw + g * 4);

    const int* parts = &p4[0].x;
    const int* us    = &u4[0].x;
    const int* vs    = &v4[0].x;

    // Compute all 16 lut addresses first so the 16 float2 gathers issue
    // back-to-back (independent, all in flight together).
    const float2* lp[16];
    #pragma unroll
    for (int j = 0; j < 16; ++j) {
        int i = parts[j] - 1;
        i = i < 0 ? 0 : (i > N_PARTS - 1 ? N_PARTS - 1 : i);
        // Faithful to reference: f32 divide, clip, *255, round-half-even.
        const float fu = fminf(fmaxf((float)us[j] / 255.0f, 0.0f), 1.0f);
        const float fv = fminf(fmaxf((float)vs[j] / 255.0f, 0.0f), 1.0f);
        const int ui = (int)rintf(fu * 255.0f);
        const int vi = (int)rintf(fv * 255.0f);
        lp[j] = (const float2*)(lut + (((size_t)i * 256 + vi) * 256 + ui) * 2);
    }
    float2 s[16];
    #pragma unroll
    for (int j = 0; j < 16; ++j) s[j] = *lp[j];

    int4 o4[4];
    int* o = &o4[0].x;
    #pragma unroll
    for (int j = 0; j < 16; ++j) {
        const int uI = (int)rintf(s[j].x * scale);
        const int vI = (int)rintf((1.0f - s[j].y) * scale);
        o[j] = (parts[j] > 0) ? (vI * R + uI) : -1;
    }
    #pragma unroll
    for (int g = 0; g < 4; ++g)
        *(int4*)(offs + (size_t)b * hw + p + g * 4) = o4[g];
}

// B*C = 128 planes, HW/(256*16) = 64 blocks per plane -> 8192 blocks.
__global__ __launch_bounds__(256) void dp_gather_kernel(
    const float* __restrict__ tex,
    const int*   __restrict__ offs,
    float*       __restrict__ out,
    int R)
{
    constexpr int C = 16, H = 512, W = 512;
    const size_t hw    = (size_t)H * W;
    const size_t plane = (size_t)R * R;

    const int bid  = blockIdx.x;
    const int xcd  = bid & 7;                // assumed XCD round-robin
    const int slot = bid >> 3;               // 0..1023 per xcd
    const int pl_local = slot >> 6;          // 0..15
    const int inner    = slot & 63;          // block within plane
    const int pidx = xcd * 16 + pl_local;    // global plane 0..127
    const int b = pidx >> 4;                 // each XCD serves one batch
    const int c = pidx & 15;

    const int px = inner * 4096 + threadIdx.x * 16;   // 16 pixels per thread

    int4 o4[4];
    #pragma unroll
    for (int g = 0; g < 4; ++g)
        o4[g] = *(const int4*)(offs + (size_t)b * hw + px + g * 4);

    const float* tc = tex + ((size_t)b * C + c) * plane;
    const int* o = &o4[0].x;

    // 16 independent gathers in flight.
    float r[16];
    #pragma unroll
    for (int j = 0; j < 16; ++j)
        r[j] = tc[o[j] >= 0 ? o[j] : 0];

    float* ob = out + ((size_t)b * C + c) * hw + px;
    #pragma unroll
    for (int g = 0; g < 4; ++g) {
        float4 w;
        w.x = (o[g * 4 + 0] >= 0) ? r[g * 4 + 0] : 0.0f;
        w.y = (o[g * 4 + 1] >= 0) ? r[g * 4 + 1] : 0.0f;
        w.z = (o[g * 4 + 2] >= 0) ? r[g * 4 + 2] : 0.0f;
        w.w = (o[g * 4 + 3] >= 0) ? r[g * 4 + 3] : 0.0f;
        *(float4*)(ob + g * 4) = w;
    }
}

// ---- fallback single-pass kernel (used only if ws_size is too small) ----
__global__ __launch_bounds__(256) void dp_fused_kernel(
    const float* __restrict__ tex,
    const int*   __restrict__ iuv,
    const float* __restrict__ lut,
    float*       __restrict__ out,
    int R)
{
    constexpr int B = 8, C = 16, H = 512, W = 512;
    const float scale = (float)(R - 1);
    const int t  = blockIdx.x * blockDim.x + threadIdx.x;
    const int WP = W / 4;
    const int w4  = (t % WP) * 4;
    const int tmp = t / WP;
    const int h   = tmp % H;
    const int b   = tmp / H;
    if (b >= B) return;

    const size_t hw    = (size_t)H * W;
    const size_t ibase = (size_t)b * 3 * hw + (size_t)h * W + w4;
    const int4 p4 = *(const int4*)(iuv + ibase);
    const int4 u4 = *(const int4*)(iuv + ibase + hw);
    const int4 v4 = *(const int4*)(iuv + ibase + 2 * hw);

    const int parts[4] = {p4.x, p4.y, p4.z, p4.w};
    const int us[4]    = {u4.x, u4.y, u4.z, u4.w};
    const int vs[4]    = {v4.x, v4.y, v4.z, v4.w};

    int  off[4]; bool m[4];
    #pragma unroll
    for (int j = 0; j < 4; ++j) {
        m[j] = parts[j] > 0;
        int i = parts[j] - 1;
        i = i < 0 ? 0 : (i > N_PARTS - 1 ? N_PARTS - 1 : i);
        const float fu = fminf(fmaxf((float)us[j] / 255.0f, 0.0f), 1.0f);
        const float fv = fminf(fmaxf((float)vs[j] / 255.0f, 0.0f), 1.0f);
        const int ui = (int)rintf(fu * 255.0f);
        const int vi = (int)rintf(fv * 255.0f);
        const float2 s = *(const float2*)(lut + (((size_t)i * 256 + vi) * 256 + ui) * 2);
        off[j] = ((int)rintf((1.0f - s.y) * scale)) * R + (int)rintf(s.x * scale);
    }

    const size_t plane = (size_t)R * R;
    const float* texb  = tex + (size_t)b * C * plane;
    float*       outb  = out + ((size_t)b * C * H + h) * W + w4;

    #pragma unroll
    for (int c = 0; c < C; ++c) {
        const float* tc = texb + (size_t)c * plane;
        float4 o;
        o.x = m[0] ? tc[off[0]] : 0.0f;
        o.y = m[1] ? tc[off[1]] : 0.0f;
        o.z = m[2] ? tc[off[2]] : 0.0f;
        o.w = m[3] ? tc[off[3]] : 0.0f;
        *(float4*)(outb + (size_t)c * hw) = o;
    }
}

extern "C" void kernel_launch(void* const* d_in, const int* in_sizes, int n_in,
                              void* d_out, int out_size, void* d_ws, size_t ws_size,
                              hipStream_t stream) {
    const float* tex = (const float*)d_in[0];
    const int*   iuv = (const int*)d_in[1];
    const float* lut = (const float*)d_in[2];
    float*       out = (float*)d_out;

    constexpr int B = 8, C = 16, H = 512, W = 512;
    // Derive R from tex element count: B*C*R*R.
    int R = 512;
    {
        long long pe = (long long)in_sizes[0] / (B * C);
        int r = 1; while ((long long)(r + 1) * (r + 1) <= pe) ++r;
        R = r;
    }

    const size_t offs_bytes = (size_t)B * H * W * sizeof(int);   // 8 MB
    if (ws_size >= offs_bytes) {
        int* offs = (int*)d_ws;
        // Pass 1: B*H*W/16 threads = 512 blocks of 256.
        dp_offsets_kernel<<<dim3(B * H * W / 16 / 256), dim3(256), 0, stream>>>(
            iuv, lut, offs, R);
        // Pass 2: 128 planes * 64 blocks = 8192 blocks of 256.
        dp_gather_kernel<<<dim3(B * C * (H * W / 4096)), dim3(256), 0, stream>>>(
            tex, offs, out, R);
    } else {
        const int threads = B * H * (W / 4);
        dp_fused_kernel<<<dim3((threads + 255) / 256), dim3(256), 0, stream>>>(
            tex, iuv, lut, out, R);
    }
}

// Round 4
// 344.062 us; speedup vs baseline: 1.2390x; 1.2390x over previous
//
#include <hip/hip_runtime.h>

// MapDensePoseTex, three-stage: (prep = tex-transpose || offsets) -> gather.
// tex (8,16,512,512) f32, iuv (8,3,512,512) i32, lut (24,256,256,2) f32,
// tex_res = 512. Output (8,16,512,512) f32.
//
// Round-3 post-mortem: gather pass is line-REQUEST-throughput bound (33.5M
// distinct-line scalar gathers, ~3.6 cyc/request). Fix: transpose tex to
// (b,y,x,c) so one texel = one 64B line; per pixel 4 dwordx4 from the SAME
// line (1 L2 request + 3 L1 merges) -> 16x fewer line requests. Transpose
// back to (c, pixel) through LDS so stores stay coalesced.

#define N_PARTS 24

// ---------------- prep: transpose (4096 blocks) + offsets (2048 blocks) ----
// Interleaved 2:1 by blockIdx so both jobs co-run across the CUs.
__global__ __launch_bounds__(256) void dp_prep_kernel(
    const float* __restrict__ tex,
    const int*   __restrict__ iuv,
    const float* __restrict__ lut,
    float*       __restrict__ texT,
    int*         __restrict__ offs)
{
    constexpr int C = 16, H = 512, W = 512, R = 512;
    constexpr size_t hw    = (size_t)H * W;
    constexpr size_t plane = (size_t)R * R;
    __shared__ float lds[16 * 516];          // 33 KB, padded rows (516)

    const int bid = blockIdx.x;              // [0, 6144)
    const int g   = bid / 3;
    const int r3  = bid - g * 3;

    if (r3 != 2) {
        // ---- transpose block: one (b, ty) texture row, 16 ch x 512 x ----
        const int tid = g * 2 + r3;          // 0..4095
        const int b  = tid >> 9;
        const int ty = tid & 511;
        const float* src = tex + (size_t)b * C * plane + (size_t)ty * R;
        const int t = threadIdx.x;

        #pragma unroll
        for (int k = 0; k < 8; ++k) {
            const int f  = k * 256 + t;      // float4 id, 0..2047
            const int c  = f >> 7;           // 128 float4 per channel row
            const int x4 = f & 127;
            const float4 v = *(const float4*)(src + (size_t)c * plane + x4 * 4);
            *(float4*)&lds[c * 516 + x4 * 4] = v;   // lane-contiguous b128, no conflict
        }
        __syncthreads();
        float* dst = texT + ((size_t)b * plane + (size_t)ty * R) * C;
        #pragma unroll
        for (int k = 0; k < 8; ++k) {
            const int f  = k * 256 + t;      // float4 id over (x, c-quad)
            const int x  = f >> 2;
            const int c0 = (f & 3) * 4;
            float4 v;
            v.x = lds[(c0 + 0) * 516 + x];   // pad 516 -> <=2-way conflicts
            v.y = lds[(c0 + 1) * 516 + x];
            v.z = lds[(c0 + 2) * 516 + x];
            v.w = lds[(c0 + 3) * 516 + x];
            *(float4*)(dst + (size_t)f * 4) = v;    // 1 KB/wave contiguous
        }
    } else {
        // ---- offsets block: 256 threads x 4 px (round-2 math, exact) ----
        const float scale = (float)(R - 1);
        const int t = g * 256 + threadIdx.x;
        const int pix4 = t * 4;
        const int b = pix4 >> 18;
        const int p = pix4 & (int)(hw - 1);

        const size_t ibase = (size_t)b * 3 * hw + p;
        const int4 p4 = *(const int4*)(iuv + ibase);
        const int4 u4 = *(const int4*)(iuv + ibase + hw);
        const int4 v4 = *(const int4*)(iuv + ibase + 2 * hw);

        const int parts[4] = {p4.x, p4.y, p4.z, p4.w};
        const int us[4]    = {u4.x, u4.y, u4.z, u4.w};
        const int vs[4]    = {v4.x, v4.y, v4.z, v4.w};

        int4 o4; int* o = &o4.x;
        #pragma unroll
        for (int j = 0; j < 4; ++j) {
            int i = parts[j] - 1;
            i = i < 0 ? 0 : (i > N_PARTS - 1 ? N_PARTS - 1 : i);
            // Faithful to reference: f32 divide, clip, *255, round-half-even.
            const float fu = fminf(fmaxf((float)us[j] / 255.0f, 0.0f), 1.0f);
            const float fv = fminf(fmaxf((float)vs[j] / 255.0f, 0.0f), 1.0f);
            const int ui = (int)rintf(fu * 255.0f);
            const int vi = (int)rintf(fv * 255.0f);
            const float2 s = *(const float2*)(lut + (((size_t)i * 256 + vi) * 256 + ui) * 2);
            const int uI = (int)rintf(s.x * scale);
            const int vI = (int)rintf((1.0f - s.y) * scale);
            o[j] = (parts[j] > 0) ? (vI * R + uI) : -1;
        }
        *(int4*)(offs + (size_t)b * hw + p) = o4;
    }
}

// ---------------- gather: 2048 blocks, 1024 px/block, 4 tiles of 256 -------
__global__ __launch_bounds__(256) void dp_gatherT_kernel(
    const float* __restrict__ texT,
    const int*   __restrict__ offs,
    float*       __restrict__ out)
{
    constexpr int C = 16;
    constexpr size_t HW = 512 * 512;
    __shared__ float lds[16 * 256];          // 16 KB tile: [c][pixel]

    const int b     = blockIdx.x & 7;        // XCD round-robin: batch per XCD
    const int inner = blockIdx.x >> 3;       // 0..255
    const int base  = inner * 1024;

    const float* tb   = texT + (size_t)b * HW * C;
    const int*   ob   = offs + (size_t)b * HW + base;
    float*       outb = out  + (size_t)b * C * HW + base;
    const int t = threadIdx.x;

    for (int tile = 0; tile < 4; ++tile) {
        const int p = tile * 256 + t;
        const int o = ob[p];                 // coalesced
        const bool m = o >= 0;
        const float4* src = (const float4*)(tb + (size_t)(m ? o : 0) * C);
        float4 r0 = src[0];                  // all four hit the SAME 64B line
        float4 r1 = src[1];
        float4 r2 = src[2];
        float4 r3 = src[3];
        if (!m) {
            r0 = r1 = r2 = r3 = make_float4(0.f, 0.f, 0.f, 0.f);
        }

        if (tile) __syncthreads();           // prior tile's LDS reads done
        lds[ 0 * 256 + t] = r0.x;  lds[ 1 * 256 + t] = r0.y;
        lds[ 2 * 256 + t] = r0.z;  lds[ 3 * 256 + t] = r0.w;
        lds[ 4 * 256 + t] = r1.x;  lds[ 5 * 256 + t] = r1.y;
        lds[ 6 * 256 + t] = r1.z;  lds[ 7 * 256 + t] = r1.w;
        lds[ 8 * 256 + t] = r2.x;  lds[ 9 * 256 + t] = r2.y;
        lds[10 * 256 + t] = r2.z;  lds[11 * 256 + t] = r2.w;
        lds[12 * 256 + t] = r3.x;  lds[13 * 256 + t] = r3.y;
        lds[14 * 256 + t] = r3.z;  lds[15 * 256 + t] = r3.w;
        __syncthreads();

        #pragma unroll
        for (int k = 0; k < 4; ++k) {
            const int idx = k * 256 + t;     // float4 id in (c, p4)
            const int c   = idx >> 6;
            const int p4  = idx & 63;
            const float4 v = *(const float4*)&lds[c * 256 + p4 * 4]; // b128, clean
            *(float4*)(outb + (size_t)c * HW + tile * 256 + p4 * 4) = v;
        }
    }
}

// ---------------- fallback kernels (round-2 path) --------------------------
__global__ __launch_bounds__(256) void dp_offsets_kernel(
    const int*   __restrict__ iuv,
    const float* __restrict__ lut,
    int*         __restrict__ offs,
    int R)
{
    constexpr int H = 512, W = 512;
    const float scale = (float)(R - 1);
    const size_t hw = (size_t)H * W;
    const int t = blockIdx.x * blockDim.x + threadIdx.x;
    const int pix4 = t * 4;
    const int b = pix4 >> 18;
    const int p = pix4 & (int)(hw - 1);

    const size_t ibase = (size_t)b * 3 * hw + p;
    const int4 p4 = *(const int4*)(iuv + ibase);
    const int4 u4 = *(const int4*)(iuv + ibase + hw);
    const int4 v4 = *(const int4*)(iuv + ibase + 2 * hw);

    const int parts[4] = {p4.x, p4.y, p4.z, p4.w};
    const int us[4]    = {u4.x, u4.y, u4.z, u4.w};
    const int vs[4]    = {v4.x, v4.y, v4.z, v4.w};

    int4 o4; int* o = &o4.x;
    #pragma unroll
    for (int j = 0; j < 4; ++j) {
        int i = parts[j] - 1;
        i = i < 0 ? 0 : (i > N_PARTS - 1 ? N_PARTS - 1 : i);
        const float fu = fminf(fmaxf((float)us[j] / 255.0f, 0.0f), 1.0f);
        const float fv = fminf(fmaxf((float)vs[j] / 255.0f, 0.0f), 1.0f);
        const int ui = (int)rintf(fu * 255.0f);
        const int vi = (int)rintf(fv * 255.0f);
        const float2 s = *(const float2*)(lut + (((size_t)i * 256 + vi) * 256 + ui) * 2);
        const int uI = (int)rintf(s.x * scale);
        const int vI = (int)rintf((1.0f - s.y) * scale);
        o[j] = (parts[j] > 0) ? (vI * R + uI) : -1;
    }
    *(int4*)(offs + (size_t)b * hw + p) = o4;
}

__global__ __launch_bounds__(256) void dp_gather_kernel(
    const float* __restrict__ tex,
    const int*   __restrict__ offs,
    float*       __restrict__ out,
    int R)
{
    constexpr int C = 16, H = 512, W = 512;
    const size_t hw    = (size_t)H * W;
    const size_t plane = (size_t)R * R;

    const int bid  = blockIdx.x;
    const int xcd  = bid & 7;
    const int slot = bid >> 3;
    const int pl_local = slot >> 8;
    const int inner    = slot & 255;
    const int pidx = xcd * 16 + pl_local;
    const int b = pidx >> 4;
    const int c = pidx & 15;

    const int px = inner * 1024 + threadIdx.x * 4;

    const int4 o4 = *(const int4*)(offs + (size_t)b * hw + px);
    const float* tc = tex + ((size_t)b * C + c) * plane;

    float4 r;
    r.x = (o4.x >= 0) ? tc[o4.x] : 0.0f;
    r.y = (o4.y >= 0) ? tc[o4.y] : 0.0f;
    r.z = (o4.z >= 0) ? tc[o4.z] : 0.0f;
    r.w = (o4.w >= 0) ? tc[o4.w] : 0.0f;

    *(float4*)(out + ((size_t)b * C + c) * hw + px) = r;
}

extern "C" void kernel_launch(void* const* d_in, const int* in_sizes, int n_in,
                              void* d_out, int out_size, void* d_ws, size_t ws_size,
                              hipStream_t stream) {
    const float* tex = (const float*)d_in[0];
    const int*   iuv = (const int*)d_in[1];
    const float* lut = (const float*)d_in[2];
    float*       out = (float*)d_out;

    constexpr int B = 8, C = 16, H = 512, W = 512;
    int R = 512;
    {
        long long pe = (long long)in_sizes[0] / (B * C);
        int r = 1; while ((long long)(r + 1) * (r + 1) <= pe) ++r;
        R = r;
    }

    const size_t texT_bytes = (size_t)B * R * R * C * sizeof(float);  // 134 MB
    const size_t offs_bytes = (size_t)B * H * W * sizeof(int);        //   8 MB

    if (R == 512 && ws_size >= texT_bytes + offs_bytes) {
        float* texT = (float*)d_ws;
        int*   offs = (int*)((char*)d_ws + texT_bytes);
        dp_prep_kernel<<<dim3(6144), dim3(256), 0, stream>>>(
            tex, iuv, lut, texT, offs);
        dp_gatherT_kernel<<<dim3(2048), dim3(256), 0, stream>>>(
            texT, offs, out);
    } else if (ws_size >= offs_bytes) {
        int* offs = (int*)d_ws;
        dp_offsets_kernel<<<dim3(B * H * W / 4 / 256), dim3(256), 0, stream>>>(
            iuv, lut, offs, R);
        dp_gather_kernel<<<dim3(B * C * (H * W / 1024)), dim3(256), 0, stream>>>(
            tex, offs, out, R);
    }
}